// Round 9
// baseline (10891.518 us; speedup 1.0000x reference)
//
#include <hip/hip_runtime.h>

typedef __attribute__((ext_vector_type(8))) short short8;
typedef __attribute__((ext_vector_type(4))) float f32x4;

// Workspace layout (bytes)
#define WS_XB     0ull          // x in bf16: [64][512][512]            33,554,432 B
#define WS_W0T    33554432ull   // layer0 weights^T fused: [4096][1536] 12,582,912 B
#define WS_W1T    46137344ull   // layer1 weights^T fused: [4096][2048] 16,777,216 B
#define WS_RING0  62914560ull   // h0 ring: [32][64][1024] bf16           4,194,304 B
#define WS_RING1  67108864ull   // h1 ring: [32][64][1024] bf16           4,194,304 B
#define WS_BAR    71303168ull   // barrier: 16 arrive words in one 64B line
#define SLOT_ELEMS 65536        // 64 batches x 1024 units per ring slot
#define SLOT_BYTES 131072

__device__ __forceinline__ unsigned short f2bf(float f) {
  unsigned u = __float_as_uint(f);
  u += 0x7FFFu + ((u >> 16) & 1u);   // round-to-nearest-even
  return (unsigned short)(u >> 16);
}

__device__ __forceinline__ float sigm(float x) { return 1.0f / (1.0f + __expf(-x)); }

// ---- sentinel: "persistent kernel never ran" (absmax ~1e6) marker ----
__global__ void sentinel_kernel(float* out) { out[0] = 1.0e6f; }

// ---- prep: fp32 -> bf16 copy of x (4 elems/thread) ----
__global__ void convert_x_kernel(const float* __restrict__ x, unsigned short* __restrict__ xb) {
  int i = blockIdx.x * 256 + threadIdx.x;
  const float4 v = ((const float4*)x)[i];
  unsigned long long pack = (unsigned long long)f2bf(v.x)
                          | ((unsigned long long)f2bf(v.y) << 16)
                          | ((unsigned long long)f2bf(v.z) << 32)
                          | ((unsigned long long)f2bf(v.w) << 48);
  ((unsigned long long*)xb)[i] = pack;
}

// ---- prep: transpose [K][4096] fp32 (Wx stacked over Wh) -> [4096 perm][Ktot] bf16 ----
__global__ void transpose_weights_kernel(const float* __restrict__ wx, const float* __restrict__ wh,
                                         unsigned short* __restrict__ dst, int Kx, int Ktot) {
  __shared__ float tile[32][33];
  const int k0 = blockIdx.x * 32, n0 = blockIdx.y * 32;
  const int tx = threadIdx.x, ty = threadIdx.y;
#pragma unroll
  for (int i = 0; i < 4; ++i) {
    int k = k0 + ty + i * 8;
    tile[ty + i * 8][tx] = (k < Kx) ? wx[(size_t)k * 4096 + n0 + tx]
                                    : wh[(size_t)(k - Kx) * 4096 + n0 + tx];
  }
  __syncthreads();
#pragma unroll
  for (int i = 0; i < 4; ++i) {
    int n = n0 + ty + i * 8;
    int r = (n & 1023) * 4 + (n >> 10);
    dst[(size_t)r * Ktot + k0 + tx] = f2bf(tile[tx][ty + i * 8]);
  }
}

// ---- per-step MFMA micro-kernel: ALL loads issued upfront, then paced waits ----
// R7/R8 lesson: the compiler sinks loads to their consumers, collapsing the
// pipeline. Structure: (1) issue every load (64 for L1) before any compute;
// sched_barrier(0) forbids reordering across the issue fence. (2) per-block
// keep-alive asm walls force each block's values to be materialized (and
// s_waitcnt'ed) right before its 16 MFMAs -- loads stay issued-early,
// waits stay late => one HBM RTT per step, not NBLK of them.
template<int N1, int NBLK>
__device__ __forceinline__ void lstm_step_mfma(int a0b, int a1b,
    const unsigned short* __restrict__ r1p, const unsigned short* __restrict__ r2p,
    f32x4& acc0, f32x4& acc1)
{
  extern __shared__ unsigned short lds[];
  short8 buf[NBLK][8];

#pragma unroll
  for (int bp = 0; bp < NBLK; ++bp) {
    const unsigned short* p = (bp < N1) ? (r1p + bp * 256) : (r2p + (bp - N1) * 256);
#pragma unroll
    for (int j = 0; j < 8; ++j) buf[bp][j] = *(const short8*)(p + j * 32);
  }
  __builtin_amdgcn_sched_barrier(0);           // every load issued before any compute

#pragma unroll
  for (int bp = 0; bp < NBLK; ++bp) {
#pragma unroll
    for (int j = 0; j < 8; ++j)
      asm volatile("" :: "v"(buf[bp][j]));     // wait-wall: block bp available here
    __builtin_amdgcn_sched_barrier(0);
#pragma unroll
    for (int j = 0; j < 8; ++j) {
      const int ko = bp * 256 + j * 32;
      short8 a0 = *(const short8*)&lds[a0b + ko];
      short8 a1 = *(const short8*)&lds[a1b + ko];
      acc0 = __builtin_amdgcn_mfma_f32_16x16x32_bf16(a0, buf[bp][j], acc0, 0, 0, 0);
      acc1 = __builtin_amdgcn_mfma_f32_16x16x32_bf16(a1, buf[bp][j], acc1, 0, 0, 0);
    }
  }
}

// ---- persistent fused 2-layer LSTM ----
// 256 WGs (1/CU). WGs [0,128): layer0; [128,256): layer1.
// DECOUPLED per-layer barriers (R8 analysis: each step's cost ~= 4 serial
// HBM-class RTTs; this cuts the barrier to ~1.5):
//   bar[0..7]  = layer0 arrive words (8 groups x 16 blocks), one 64B line
//   bar[8..15] = layer1 arrive words
// tid0 fetch-adds its group word; lanes 0-15 of wave 0 poll ALL 16 words with
// one coalesced atomic load + ballot. Exit conditions:
//   L0 end of episode s: words[0..7] >= 16(s+1)  (own layer)
//                        words[8..15] >= 16(s-29) (ring anti-clobber: L0 may
//                        lead L1 by at most 30 episodes < ring depth 32)
//   L1 end of episode s: all 16 words >= 16(s+1)  (own layer + h0[s] ready;
//                        L0 runs ahead so the word0 check passes on poll #1)
// Coherence: h writes = atomic exchange (RMW -> coherence point); h reads =
// plain loads, fresh via depth-32 ring capacity eviction (R8-proven).
__global__ void __launch_bounds__(256, 1) lstm_persistent(
    const unsigned short* __restrict__ xb,
    const unsigned short* __restrict__ w0t,
    const unsigned short* __restrict__ w1t,
    const float* __restrict__ b0v, const float* __restrict__ b1v,
    unsigned short* __restrict__ ring0, unsigned short* __restrict__ ring1,
    unsigned* __restrict__ bar,
    float* __restrict__ out)
{
  extern __shared__ unsigned short lds[];

  const int wg    = blockIdx.x;
  const int group = wg >> 7;       // 0: layer0, 1: layer1
  const int wgl   = wg & 127;
  const int hu0   = wgl * 8;
  const int tid   = threadIdx.x;
  const int lane  = tid & 63;
  const int wid   = tid >> 6;
  const int c16   = lane & 15;
  const int row4  = lane >> 4;
  const int bb    = wid * 16 + c16; // this lane's batch

  const int K    = group ? 2048 : 1536;
  const int KPAD = group ? 2050 : 1538;   // stride ≡1 mod 32 dwords: conflict-free A-reads

  { // stage weight slice global -> LDS, permuted: LDS row r <- slice row
    // src(r) = 8*((r&15)>>2) + 4*(r>>4) + (r&3)  (tile0 even-of-pair, tile1 odd)
    const unsigned short* wsrc = (group ? w1t : w0t) + (size_t)(wgl * 32) * K;
    const int kv = K >> 3;
    for (int c = tid; c < 32 * kv; c += 256) {
      int r = c / kv, q = c - r * kv;
      int srcr = 8 * ((r & 15) >> 2) + 4 * (r >> 4) + (r & 3);
      *(short8*)&lds[r * KPAD + q * 8] = *(const short8*)&wsrc[(size_t)srcr * K + q * 8];
    }
  }
  __syncthreads();

  const float* bsrc = group ? b1v : b0v;
  float bias0[4], bias1[4];
#pragma unroll
  for (int j = 0; j < 4; ++j) {
    bias0[j] = bsrc[j * 1024 + hu0 + 2 * row4];       // even unit of pair
    bias1[j] = bsrc[j * 1024 + hu0 + 2 * row4 + 1];   // odd unit of pair
  }

  const int a0b = c16 * KPAD + 8 * row4;
  const int a1b = a0b + 16 * KPAD;

  const int lofs = (bb << 10) + 8 * row4;              // read offset within a slot
  const unsigned short* x_cur = xb + ((size_t)bb << 18) + 8 * row4;  // +512/step
  unsigned* rwb = (unsigned*)(group ? ring1 : ring0) + (((bb << 10) + hu0) >> 1) + row4;
  float* out_base = out + ((size_t)bb << 19) + hu0 + 2 * row4;

  float cst0 = 0.0f, cst1 = 0.0f;

  auto compute_episode = [&](int s) {
    const int t = group ? (s - 1) : s;

    f32x4 acc0 = { bias0[0], bias0[1], bias0[2], bias0[3] };
    f32x4 acc1 = { bias1[0], bias1[1], bias1[2], bias1[3] };

    const unsigned short* h0rd = ring0 + ((s - 1) & 31) * SLOT_ELEMS + lofs;  // h0[s-1]
    if (group == 0) {
      lstm_step_mfma<2, 6>(a0b, a1b, x_cur, h0rd, acc0, acc1);
      x_cur += 512;
    } else {
      const unsigned short* h1rd = ring1 + ((s - 2) & 31) * SLOT_ELEMS + lofs; // h1[s-2]
      lstm_step_mfma<4, 8>(a0b, a1b, h0rd, h1rd, acc0, acc1);
    }

    float hv0, hv1;
    {
      float iv = sigm(acc0[0]), fv = sigm(acc0[1]);
      float gv = tanhf(acc0[2]), ov = sigm(acc0[3]);
      cst0 = fv * cst0 + iv * gv;
      hv0 = ov * tanhf(cst0);
    }
    {
      float iv = sigm(acc1[0]), fv = sigm(acc1[1]);
      float gv = tanhf(acc1[2]), ov = sigm(acc1[3]);
      cst1 = fv * cst1 + iv * gv;
      hv1 = ov * tanhf(cst1);
    }
    // h write: RMW exchange -> coherence point; slot t&31.
    unsigned hp = (unsigned)f2bf(hv0) | ((unsigned)f2bf(hv1) << 16);
    (void)__hip_atomic_exchange(rwb + (t & 31) * (SLOT_ELEMS / 2), hp,
                                __ATOMIC_RELAXED, __HIP_MEMORY_SCOPE_AGENT);
    if (group) {
      float2 o2; o2.x = hv0; o2.y = hv1;
      *(float2*)(out_base + ((size_t)t << 10)) = o2;   // plain; flushed at dispatch end
    }
  };

  for (int s = 0; s < 512; ++s) {
    const bool active = group ? (s >= 1) : true;
    if (active) compute_episode(s);

    // ---- single-hop split barrier (end of episode s) ----
    __syncthreads();   // drains all waves' vmem: exchanges at coherence point
    if (wid == 0) {
      if (lane == 0)
        __hip_atomic_fetch_add(bar + (wg >> 4), 1u, __ATOMIC_RELAXED, __HIP_MEMORY_SCOPE_AGENT);
      const bool last = (group == 0) && (s == 511);    // L0: nothing left to wait for
      if (!last) {
        int tgt;
        if (group == 0) tgt = (lane < 8) ? 16 * (s + 1) : 16 * (s - 29);
        else            tgt = 16 * (s + 1);
        for (;;) {
          int v = (lane < 16)
            ? (int)__hip_atomic_load(bar + lane, __ATOMIC_RELAXED, __HIP_MEMORY_SCOPE_AGENT)
            : 0x7FFFFFFF;
          if (__ballot(v >= tgt) == ~0ull) break;
          __builtin_amdgcn_s_sleep(1);
        }
      }
    }
    __syncthreads();
  }
  // L1 final episode (t=511): inputs guaranteed by the s=511 barrier exit.
  if (group) compute_episode(512);
}

extern "C" void kernel_launch(void* const* d_in, const int* in_sizes, int n_in,
                              void* d_out, int out_size, void* d_ws, size_t ws_size,
                              hipStream_t stream) {
  const float* x   = (const float*)d_in[0];
  const float* Wx0 = (const float*)d_in[1];
  const float* Wh0 = (const float*)d_in[2];
  const float* b0  = (const float*)d_in[3];
  const float* Wx1 = (const float*)d_in[4];
  const float* Wh1 = (const float*)d_in[5];
  const float* b1  = (const float*)d_in[6];
  float* outp = (float*)d_out;

  char* ws = (char*)d_ws;
  unsigned short* xbp   = (unsigned short*)(ws + WS_XB);
  unsigned short* w0tp  = (unsigned short*)(ws + WS_W0T);
  unsigned short* w1tp  = (unsigned short*)(ws + WS_W1T);
  unsigned short* ring0 = (unsigned short*)(ws + WS_RING0);
  unsigned short* ring1 = (unsigned short*)(ws + WS_RING1);
  unsigned*       barp  = (unsigned*)(ws + WS_BAR);

  // prep
  sentinel_kernel<<<dim3(1), dim3(1), 0, stream>>>(outp);
  convert_x_kernel<<<dim3(16384), dim3(256), 0, stream>>>(x, xbp);
  transpose_weights_kernel<<<dim3(48, 128), dim3(32, 8), 0, stream>>>(Wx0, Wh0, w0tp, 512, 1536);
  transpose_weights_kernel<<<dim3(64, 128), dim3(32, 8), 0, stream>>>(Wx1, Wh1, w1tp, 1024, 2048);
  // zero the t=-1 slots (slot 31 of each ring) + barrier words
  hipMemsetAsync(ring0 + 31 * SLOT_ELEMS, 0, SLOT_BYTES, stream);
  hipMemsetAsync(ring1 + 31 * SLOT_ELEMS, 0, SLOT_BYTES, stream);
  hipMemsetAsync(barp, 0, 4096, stream);

  // persistent fused kernel; prefer cooperative launch, fall back to a plain
  // launch (256 blocks x 1 block/CU is co-resident on 256 CUs) if it fails.
  void* kargs[] = { (void*)&xbp, (void*)&w0tp, (void*)&w1tp, (void*)&b0, (void*)&b1,
                    (void*)&ring0, (void*)&ring1, (void*)&barp, (void*)&outp };
  hipError_t e = hipLaunchCooperativeKernel((void*)lstm_persistent, dim3(256), dim3(256),
                                            kargs, 32 * 2050 * 2 /* 131,200 B LDS */, stream);
  if (e != hipSuccess) {
    lstm_persistent<<<dim3(256), dim3(256), 32 * 2050 * 2, stream>>>(
        xbp, w0tp, w1tp, b0, b1, ring0, ring1, barp, outp);
  }
}

// Round 10
// 10310.622 us; speedup vs baseline: 1.0563x; 1.0563x over previous
//
#include <hip/hip_runtime.h>

typedef __attribute__((ext_vector_type(8))) short short8;
typedef __attribute__((ext_vector_type(4))) float f32x4;

// Workspace layout (bytes)
#define WS_XB     0ull          // x in bf16: [64][512][512]            33,554,432 B
#define WS_W0T    33554432ull   // layer0 weights^T fused: [4096][1536] 12,582,912 B
#define WS_W1T    46137344ull   // layer1 weights^T fused: [4096][2048] 16,777,216 B
#define WS_RING0  62914560ull   // h0 ring: [32][64][1024] bf16           4,194,304 B
#define WS_RING1  67108864ull   // h1 ring: [32][64][1024] bf16           4,194,304 B
#define WS_BAR    71303168ull   // barrier: root word + 16 release lines
#define SLOT_ELEMS 65536        // 64 batches x 1024 units per ring slot
#define SLOT_BYTES 131072

__device__ __forceinline__ unsigned short f2bf(float f) {
  unsigned u = __float_as_uint(f);
  u += 0x7FFFu + ((u >> 16) & 1u);   // round-to-nearest-even
  return (unsigned short)(u >> 16);
}

__device__ __forceinline__ float sigm(float x) { return 1.0f / (1.0f + __expf(-x)); }

// ---- sentinel: "persistent kernel never ran" (absmax ~1e6) marker ----
__global__ void sentinel_kernel(float* out) { out[0] = 1.0e6f; }

// ---- prep: fp32 -> bf16 copy of x (4 elems/thread) ----
__global__ void convert_x_kernel(const float* __restrict__ x, unsigned short* __restrict__ xb) {
  int i = blockIdx.x * 256 + threadIdx.x;
  const float4 v = ((const float4*)x)[i];
  unsigned long long pack = (unsigned long long)f2bf(v.x)
                          | ((unsigned long long)f2bf(v.y) << 16)
                          | ((unsigned long long)f2bf(v.z) << 32)
                          | ((unsigned long long)f2bf(v.w) << 48);
  ((unsigned long long*)xb)[i] = pack;
}

// ---- prep: transpose [K][4096] fp32 (Wx stacked over Wh) -> [4096 perm][Ktot] bf16 ----
__global__ void transpose_weights_kernel(const float* __restrict__ wx, const float* __restrict__ wh,
                                         unsigned short* __restrict__ dst, int Kx, int Ktot) {
  __shared__ float tile[32][33];
  const int k0 = blockIdx.x * 32, n0 = blockIdx.y * 32;
  const int tx = threadIdx.x, ty = threadIdx.y;
#pragma unroll
  for (int i = 0; i < 4; ++i) {
    int k = k0 + ty + i * 8;
    tile[ty + i * 8][tx] = (k < Kx) ? wx[(size_t)k * 4096 + n0 + tx]
                                    : wh[(size_t)(k - Kx) * 4096 + n0 + tx];
  }
  __syncthreads();
#pragma unroll
  for (int i = 0; i < 4; ++i) {
    int n = n0 + ty + i * 8;
    int r = (n & 1023) * 4 + (n >> 10);
    dst[(size_t)r * Ktot + k0 + tx] = f2bf(tile[tx][ty + i * 8]);
  }
}

// ---- per-step MFMA micro-kernel: 4-deep pipeline with NAMED slots ----
// R8's buf[bp&3] rotation collapsed to ~2 live slots (VGPR 92): the compiler's
// array-index analysis let it re-sink loads. Named slot variables + explicit
// schedule + sched_barrier(0) after each issue pin 4 blocks (32 x 16B loads)
// in flight. R9's all-upfront variant (8 blocks, 256 buf VGPRs) risks spills;
// 4-deep fits ~170 VGPRs.
template<int N1, int NBLK>
__device__ __forceinline__ void lstm_step_mfma(int a0b, int a1b,
    const unsigned short* __restrict__ r1p, const unsigned short* __restrict__ r2p,
    f32x4& acc0, f32x4& acc1)
{
  extern __shared__ unsigned short lds[];
  short8 s0[8], s1[8], s2[8], s3[8];

  auto ldp = [&](int blk) { return (blk < N1) ? (r1p + blk * 256) : (r2p + (blk - N1) * 256); };
  auto issue = [&](short8* dst, int blk) {
    const unsigned short* p = ldp(blk);
#pragma unroll
    for (int j = 0; j < 8; ++j) dst[j] = *(const short8*)(p + j * 32);
  };
  auto compute8 = [&](const short8* b, int bp) {
#pragma unroll
    for (int j = 0; j < 8; ++j) {
      const int ko = bp * 256 + j * 32;
      short8 a0 = *(const short8*)&lds[a0b + ko];
      short8 a1 = *(const short8*)&lds[a1b + ko];
      acc0 = __builtin_amdgcn_mfma_f32_16x16x32_bf16(a0, b[j], acc0, 0, 0, 0);
      acc1 = __builtin_amdgcn_mfma_f32_16x16x32_bf16(a1, b[j], acc1, 0, 0, 0);
    }
  };

  issue(s0, 0); issue(s1, 1); issue(s2, 2); issue(s3, 3);
  __builtin_amdgcn_sched_barrier(0);
  compute8(s0, 0); if (NBLK > 4) { issue(s0, 4); __builtin_amdgcn_sched_barrier(0); }
  compute8(s1, 1); if (NBLK > 5) { issue(s1, 5); __builtin_amdgcn_sched_barrier(0); }
  compute8(s2, 2); if (NBLK > 6) { issue(s2, 6); __builtin_amdgcn_sched_barrier(0); }
  compute8(s3, 3); if (NBLK > 7) { issue(s3, 7); __builtin_amdgcn_sched_barrier(0); }
  if (NBLK > 4) compute8(s0, 4);
  if (NBLK > 5) compute8(s1, 5);
  if (NBLK > 6) compute8(s2, 6);
  if (NBLK > 7) compute8(s3, 7);
}

// ---- persistent fused 2-layer LSTM ----
// 256 WGs (1/CU). WGs [0,128): layer0; [128,256): layer1 one step behind,
// LOCKSTEP via one shared barrier per episode (R9's decoupling regressed).
// Coherence (R7/R8-proven): h writes = atomic exchange (RMW -> coherence
// point); h reads = plain loads kept fresh by depth-32 ring capacity
// eviction. No buffer_inv.
// Barrier (flattened vs R8, one hop fewer):
//   arrive: every block's tid0 fetch_adds ONE root word (serialized RMWs at
//           MALL overlap arrival skew);
//   release: the last arriver (old == 256(s+1)-1) exchanges 16 release words
//           on SEPARATE 64B lines; each tid0 polls only its group's word
//           (16 blocks/line -- R8's proven poll pattern; R9 lesson: never
//           lane-gather-poll a single line, it serializes at MALL).
__global__ void __launch_bounds__(256, 1) lstm_persistent(
    const unsigned short* __restrict__ xb,
    const unsigned short* __restrict__ w0t,
    const unsigned short* __restrict__ w1t,
    const float* __restrict__ b0v, const float* __restrict__ b1v,
    unsigned short* __restrict__ ring0, unsigned short* __restrict__ ring1,
    unsigned* __restrict__ bar,
    float* __restrict__ out)
{
  extern __shared__ unsigned short lds[];

  const int wg    = blockIdx.x;
  const int group = wg >> 7;       // 0: layer0, 1: layer1
  const int wgl   = wg & 127;
  const int hu0   = wgl * 8;
  const int tid   = threadIdx.x;
  const int lane  = tid & 63;
  const int wid   = tid >> 6;
  const int c16   = lane & 15;
  const int row4  = lane >> 4;
  const int bb    = wid * 16 + c16; // this lane's batch

  const int K    = group ? 2048 : 1536;
  const int KPAD = group ? 2050 : 1538;   // stride: bank-conflict-free (R9: conflicts -> 0)

  { // stage weight slice global -> LDS, permuted: LDS row r <- slice row
    // src(r) = 8*((r&15)>>2) + 4*(r>>4) + (r&3)  (tile0 even-of-pair, tile1 odd)
    const unsigned short* wsrc = (group ? w1t : w0t) + (size_t)(wgl * 32) * K;
    const int kv = K >> 3;
    for (int c = tid; c < 32 * kv; c += 256) {
      int r = c / kv, q = c - r * kv;
      int srcr = 8 * ((r & 15) >> 2) + 4 * (r >> 4) + (r & 3);
      *(short8*)&lds[r * KPAD + q * 8] = *(const short8*)&wsrc[(size_t)srcr * K + q * 8];
    }
  }
  __syncthreads();

  const float* bsrc = group ? b1v : b0v;
  float bias0[4], bias1[4];
#pragma unroll
  for (int j = 0; j < 4; ++j) {
    bias0[j] = bsrc[j * 1024 + hu0 + 2 * row4];       // even unit of pair
    bias1[j] = bsrc[j * 1024 + hu0 + 2 * row4 + 1];   // odd unit of pair
  }

  const int a0b = c16 * KPAD + 8 * row4;
  const int a1b = a0b + 16 * KPAD;

  const int lofs = (bb << 10) + 8 * row4;              // read offset within a slot
  const unsigned short* x_cur = xb + ((size_t)bb << 18) + 8 * row4;  // +512/step
  unsigned* rwb = (unsigned*)(group ? ring1 : ring0) + (((bb << 10) + hu0) >> 1) + row4;
  float* out_base = out + ((size_t)bb << 19) + hu0 + 2 * row4;

  unsigned* rootc = bar;                   // arrive word
  unsigned* relc  = bar + 16 + (wg >> 4) * 16;   // this group's release line

  float cst0 = 0.0f, cst1 = 0.0f;

  for (int s = 0; s <= 512; ++s) {
    const bool active = group ? (s >= 1) : (s < 512);
    if (active) {
      const int t = group ? (s - 1) : s;

      f32x4 acc0 = { bias0[0], bias0[1], bias0[2], bias0[3] };
      f32x4 acc1 = { bias1[0], bias1[1], bias1[2], bias1[3] };

      const unsigned short* h0rd = ring0 + ((s - 1) & 31) * SLOT_ELEMS + lofs;  // h0[s-1]
      if (group == 0) {
        lstm_step_mfma<2, 6>(a0b, a1b, x_cur, h0rd, acc0, acc1);
        x_cur += 512;
      } else {
        const unsigned short* h1rd = ring1 + ((s - 2) & 31) * SLOT_ELEMS + lofs; // h1[s-2]
        lstm_step_mfma<4, 8>(a0b, a1b, h0rd, h1rd, acc0, acc1);
      }

      float hv0, hv1;
      {
        float iv = sigm(acc0[0]), fv = sigm(acc0[1]);
        float gv = tanhf(acc0[2]), ov = sigm(acc0[3]);
        cst0 = fv * cst0 + iv * gv;
        hv0 = ov * tanhf(cst0);
      }
      {
        float iv = sigm(acc1[0]), fv = sigm(acc1[1]);
        float gv = tanhf(acc1[2]), ov = sigm(acc1[3]);
        cst1 = fv * cst1 + iv * gv;
        hv1 = ov * tanhf(cst1);
      }
      // h write: RMW exchange -> coherence point; slot t&31.
      unsigned hp = (unsigned)f2bf(hv0) | ((unsigned)f2bf(hv1) << 16);
      (void)__hip_atomic_exchange(rwb + (t & 31) * (SLOT_ELEMS / 2), hp,
                                  __ATOMIC_RELAXED, __HIP_MEMORY_SCOPE_AGENT);
      if (group) {
        float2 o2; o2.x = hv0; o2.y = hv1;
        *(float2*)(out_base + ((size_t)t << 10)) = o2;   // plain; flushed at dispatch end
      }
    }

    // ---- flat single-root grid barrier (episode s) ----
    __syncthreads();   // drains all waves' vmem: exchanges at coherence point
    if (tid == 0) {
      unsigned old = __hip_atomic_fetch_add(rootc, 1u, __ATOMIC_RELAXED, __HIP_MEMORY_SCOPE_AGENT);
      if (old == 256u * (unsigned)(s + 1) - 1u) {        // globally last arriver
#pragma unroll
        for (int g2 = 0; g2 < 16; ++g2)
          (void)__hip_atomic_exchange(bar + 16 + g2 * 16, (unsigned)(s + 1),
                                      __ATOMIC_RELAXED, __HIP_MEMORY_SCOPE_AGENT);
      }
      while (__hip_atomic_load(relc, __ATOMIC_RELAXED, __HIP_MEMORY_SCOPE_AGENT) < (unsigned)(s + 1))
        __builtin_amdgcn_s_sleep(1);
    }
    __syncthreads();
  }
}

extern "C" void kernel_launch(void* const* d_in, const int* in_sizes, int n_in,
                              void* d_out, int out_size, void* d_ws, size_t ws_size,
                              hipStream_t stream) {
  const float* x   = (const float*)d_in[0];
  const float* Wx0 = (const float*)d_in[1];
  const float* Wh0 = (const float*)d_in[2];
  const float* b0  = (const float*)d_in[3];
  const float* Wx1 = (const float*)d_in[4];
  const float* Wh1 = (const float*)d_in[5];
  const float* b1  = (const float*)d_in[6];
  float* outp = (float*)d_out;

  char* ws = (char*)d_ws;
  unsigned short* xbp   = (unsigned short*)(ws + WS_XB);
  unsigned short* w0tp  = (unsigned short*)(ws + WS_W0T);
  unsigned short* w1tp  = (unsigned short*)(ws + WS_W1T);
  unsigned short* ring0 = (unsigned short*)(ws + WS_RING0);
  unsigned short* ring1 = (unsigned short*)(ws + WS_RING1);
  unsigned*       barp  = (unsigned*)(ws + WS_BAR);

  // prep
  sentinel_kernel<<<dim3(1), dim3(1), 0, stream>>>(outp);
  convert_x_kernel<<<dim3(16384), dim3(256), 0, stream>>>(x, xbp);
  transpose_weights_kernel<<<dim3(48, 128), dim3(32, 8), 0, stream>>>(Wx0, Wh0, w0tp, 512, 1536);
  transpose_weights_kernel<<<dim3(64, 128), dim3(32, 8), 0, stream>>>(Wx1, Wh1, w1tp, 1024, 2048);
  // zero the t=-1 slots (slot 31 of each ring) + barrier words
  hipMemsetAsync(ring0 + 31 * SLOT_ELEMS, 0, SLOT_BYTES, stream);
  hipMemsetAsync(ring1 + 31 * SLOT_ELEMS, 0, SLOT_BYTES, stream);
  hipMemsetAsync(barp, 0, 4096, stream);

  // persistent fused kernel; prefer cooperative launch, fall back to a plain
  // launch (256 blocks x 1 block/CU is co-resident on 256 CUs) if it fails.
  void* kargs[] = { (void*)&xbp, (void*)&w0tp, (void*)&w1tp, (void*)&b0, (void*)&b1,
                    (void*)&ring0, (void*)&ring1, (void*)&barp, (void*)&outp };
  hipError_t e = hipLaunchCooperativeKernel((void*)lstm_persistent, dim3(256), dim3(256),
                                            kargs, 32 * 2050 * 2 /* 131,200 B LDS */, stream);
  if (e != hipSuccess) {
    lstm_persistent<<<dim3(256), dim3(256), 32 * 2050 * 2, stream>>>(
        xbp, w0tp, w1tp, b0, b1, ring0, ring1, barp, outp);
  }
}

// Round 11
// 9842.278 us; speedup vs baseline: 1.1066x; 1.0476x over previous
//
#include <hip/hip_runtime.h>

typedef __attribute__((ext_vector_type(8))) short short8;
typedef __attribute__((ext_vector_type(4))) float f32x4;

// Workspace layout (bytes)
#define WS_XB     0ull          // x in bf16: [64][512][512]            33,554,432 B
#define WS_W0T    33554432ull   // layer0 weights^T fused: [4096][1536] 12,582,912 B
#define WS_W1T    46137344ull   // layer1 weights^T fused: [4096][2048] 16,777,216 B
#define WS_RING0  62914560ull   // h0 ring: [32][64][1024] bf16           4,194,304 B
#define WS_RING1  67108864ull   // h1 ring: [32][64][1024] bf16           4,194,304 B
#define WS_BAR    71303168ull   // barrier counters (<=4096 B used)
#define SLOT_ELEMS 65536        // 64 batches x 1024 units per ring slot
#define SLOT_BYTES 131072

// Barrier word offsets (x4 B): arrive[g]=g*16 (separate 64B lines), root=256,
// release[g]=272+g*16 (separate 64B lines).
// R9/R10 laws: never >16 same-line RMWs per episode; never lane-gather-poll
// one line; fan-out on separate lines. This is R8's proven structure.
#define BAR_ARR(g)  ((g) * 16)
#define BAR_ROOT    256
#define BAR_REL(g)  (272 + (g) * 16)

__device__ __forceinline__ unsigned short f2bf(float f) {
  unsigned u = __float_as_uint(f);
  u += 0x7FFFu + ((u >> 16) & 1u);   // round-to-nearest-even
  return (unsigned short)(u >> 16);
}

__device__ __forceinline__ float sigm(float x) { return 1.0f / (1.0f + __expf(-x)); }

// ---- sentinel: "persistent kernel never ran" (absmax ~1e6) marker ----
__global__ void sentinel_kernel(float* out) { out[0] = 1.0e6f; }

// ---- prep: fp32 -> bf16 copy of x (4 elems/thread) ----
__global__ void convert_x_kernel(const float* __restrict__ x, unsigned short* __restrict__ xb) {
  int i = blockIdx.x * 256 + threadIdx.x;
  const float4 v = ((const float4*)x)[i];
  unsigned long long pack = (unsigned long long)f2bf(v.x)
                          | ((unsigned long long)f2bf(v.y) << 16)
                          | ((unsigned long long)f2bf(v.z) << 32)
                          | ((unsigned long long)f2bf(v.w) << 48);
  ((unsigned long long*)xb)[i] = pack;
}

// ---- prep: transpose [K][4096] fp32 (Wx stacked over Wh) -> [4096 perm][Ktot] bf16 ----
__global__ void transpose_weights_kernel(const float* __restrict__ wx, const float* __restrict__ wh,
                                         unsigned short* __restrict__ dst, int Kx, int Ktot) {
  __shared__ float tile[32][33];
  const int k0 = blockIdx.x * 32, n0 = blockIdx.y * 32;
  const int tx = threadIdx.x, ty = threadIdx.y;
#pragma unroll
  for (int i = 0; i < 4; ++i) {
    int k = k0 + ty + i * 8;
    tile[ty + i * 8][tx] = (k < Kx) ? wx[(size_t)k * 4096 + n0 + tx]
                                    : wh[(size_t)(k - Kx) * 4096 + n0 + tx];
  }
  __syncthreads();
#pragma unroll
  for (int i = 0; i < 4; ++i) {
    int n = n0 + ty + i * 8;
    int r = (n & 1023) * 4 + (n >> 10);
    dst[(size_t)r * Ktot + k0 + tx] = f2bf(tile[tx][ty + i * 8]);
  }
}

// ---- per-step MFMA micro-kernel: ALL loads issued upfront (R9 body, VGPR 156
// ---- = the only structure that measurably deepened the pipeline) ----
template<int N1, int NBLK>
__device__ __forceinline__ void lstm_step_mfma(int a0b, int a1b,
    const unsigned short* __restrict__ r1p, const unsigned short* __restrict__ r2p,
    f32x4& acc0, f32x4& acc1)
{
  extern __shared__ unsigned short lds[];
  short8 buf[NBLK][8];

#pragma unroll
  for (int bp = 0; bp < NBLK; ++bp) {
    const unsigned short* p = (bp < N1) ? (r1p + bp * 256) : (r2p + (bp - N1) * 256);
#pragma unroll
    for (int j = 0; j < 8; ++j) buf[bp][j] = *(const short8*)(p + j * 32);
  }
  __builtin_amdgcn_sched_barrier(0);           // every load issued before any compute

#pragma unroll
  for (int bp = 0; bp < NBLK; ++bp) {
#pragma unroll
    for (int j = 0; j < 8; ++j)
      asm volatile("" :: "v"(buf[bp][j]));     // wait-wall: block bp materialized here
    __builtin_amdgcn_sched_barrier(0);
#pragma unroll
    for (int j = 0; j < 8; ++j) {
      const int ko = bp * 256 + j * 32;
      short8 a0 = *(const short8*)&lds[a0b + ko];
      short8 a1 = *(const short8*)&lds[a1b + ko];
      acc0 = __builtin_amdgcn_mfma_f32_16x16x32_bf16(a0, buf[bp][j], acc0, 0, 0, 0);
      acc1 = __builtin_amdgcn_mfma_f32_16x16x32_bf16(a1, buf[bp][j], acc1, 0, 0, 0);
    }
  }
}

// ---- persistent fused 2-layer LSTM ----
// 256 WGs (1/CU). WGs [0,128): layer0; [128,256): layer1 one step behind,
// lockstep. Weights LDS-resident, KPAD stride 2050/1538 (conflict-free).
// Coherence (R7/R8-proven): h writes = atomic exchange (RMW -> coherence
// point); h reads = plain loads, fresh via depth-32 ring capacity eviction.
// Barrier = R8's two-level tree (best measured: ~3.3us/step).
__global__ void __launch_bounds__(256, 1) lstm_persistent(
    const unsigned short* __restrict__ xb,
    const unsigned short* __restrict__ w0t,
    const unsigned short* __restrict__ w1t,
    const float* __restrict__ b0v, const float* __restrict__ b1v,
    unsigned short* __restrict__ ring0, unsigned short* __restrict__ ring1,
    unsigned* __restrict__ bar,
    float* __restrict__ out)
{
  extern __shared__ unsigned short lds[];

  const int wg    = blockIdx.x;
  const int group = wg >> 7;       // 0: layer0, 1: layer1
  const int wgl   = wg & 127;
  const int hu0   = wgl * 8;
  const int tid   = threadIdx.x;
  const int lane  = tid & 63;
  const int wid   = tid >> 6;
  const int c16   = lane & 15;
  const int row4  = lane >> 4;
  const int bb    = wid * 16 + c16; // this lane's batch

  const int K    = group ? 2048 : 1536;
  const int KPAD = group ? 2050 : 1538;   // stride: bank-conflict-free (R9/R10: conflicts -> 0)

  { // stage weight slice global -> LDS, permuted: LDS row r <- slice row
    // src(r) = 8*((r&15)>>2) + 4*(r>>4) + (r&3)  (tile0 even-of-pair, tile1 odd)
    const unsigned short* wsrc = (group ? w1t : w0t) + (size_t)(wgl * 32) * K;
    const int kv = K >> 3;
    for (int c = tid; c < 32 * kv; c += 256) {
      int r = c / kv, q = c - r * kv;
      int srcr = 8 * ((r & 15) >> 2) + 4 * (r >> 4) + (r & 3);
      *(short8*)&lds[r * KPAD + q * 8] = *(const short8*)&wsrc[(size_t)srcr * K + q * 8];
    }
  }
  __syncthreads();

  const float* bsrc = group ? b1v : b0v;
  float bias0[4], bias1[4];
#pragma unroll
  for (int j = 0; j < 4; ++j) {
    bias0[j] = bsrc[j * 1024 + hu0 + 2 * row4];       // even unit of pair
    bias1[j] = bsrc[j * 1024 + hu0 + 2 * row4 + 1];   // odd unit of pair
  }

  const int a0b = c16 * KPAD + 8 * row4;
  const int a1b = a0b + 16 * KPAD;

  const int lofs = (bb << 10) + 8 * row4;              // read offset within a slot
  const unsigned short* x_cur = xb + ((size_t)bb << 18) + 8 * row4;  // +512/step
  unsigned* rwb = (unsigned*)(group ? ring1 : ring0) + (((bb << 10) + hu0) >> 1) + row4;
  float* out_base = out + ((size_t)bb << 19) + hu0 + 2 * row4;

  // R8 barrier bookkeeping: 16 groups of 16 blocks.
  const int mygrp = wg >> 4;
  unsigned* grpc  = bar + BAR_ARR(mygrp);
  unsigned* rootc = bar + BAR_ROOT;
  unsigned* relc  = bar + BAR_REL(mygrp);

  float cst0 = 0.0f, cst1 = 0.0f;

  for (int s = 0; s <= 512; ++s) {
    const bool active = group ? (s >= 1) : (s < 512);
    if (active) {
      const int t = group ? (s - 1) : s;

      f32x4 acc0 = { bias0[0], bias0[1], bias0[2], bias0[3] };
      f32x4 acc1 = { bias1[0], bias1[1], bias1[2], bias1[3] };

      const unsigned short* h0rd = ring0 + ((s - 1) & 31) * SLOT_ELEMS + lofs;  // h0[s-1]
      if (group == 0) {
        lstm_step_mfma<2, 6>(a0b, a1b, x_cur, h0rd, acc0, acc1);
        x_cur += 512;
      } else {
        const unsigned short* h1rd = ring1 + ((s - 2) & 31) * SLOT_ELEMS + lofs; // h1[s-2]
        lstm_step_mfma<4, 8>(a0b, a1b, h0rd, h1rd, acc0, acc1);
      }

      float hv0, hv1;
      {
        float iv = sigm(acc0[0]), fv = sigm(acc0[1]);
        float gv = tanhf(acc0[2]), ov = sigm(acc0[3]);
        cst0 = fv * cst0 + iv * gv;
        hv0 = ov * tanhf(cst0);
      }
      {
        float iv = sigm(acc1[0]), fv = sigm(acc1[1]);
        float gv = tanhf(acc1[2]), ov = sigm(acc1[3]);
        cst1 = fv * cst1 + iv * gv;
        hv1 = ov * tanhf(cst1);
      }
      // h write: RMW exchange -> coherence point; slot t&31.
      unsigned hp = (unsigned)f2bf(hv0) | ((unsigned)f2bf(hv1) << 16);
      (void)__hip_atomic_exchange(rwb + (t & 31) * (SLOT_ELEMS / 2), hp,
                                  __ATOMIC_RELAXED, __HIP_MEMORY_SCOPE_AGENT);
      if (group) {
        float2 o2; o2.x = hv0; o2.y = hv1;
        *(float2*)(out_base + ((size_t)t << 10)) = o2;   // plain; flushed at dispatch end
      }
    }

    // ---- R8 two-level grid barrier (episode s) ----
    __syncthreads();   // drains all waves' vmem: exchanges at coherence point
    if (tid == 0) {
      unsigned old = __hip_atomic_fetch_add(grpc, 1u, __ATOMIC_RELAXED, __HIP_MEMORY_SCOPE_AGENT);
      if (old == (unsigned)(16 * s + 15)) {                 // group complete
        unsigned old2 = __hip_atomic_fetch_add(rootc, 1u, __ATOMIC_RELAXED, __HIP_MEMORY_SCOPE_AGENT);
        if (old2 == (unsigned)(16 * s + 15)) {              // globally last
#pragma unroll
          for (int g2 = 0; g2 < 16; ++g2)
            (void)__hip_atomic_exchange(bar + BAR_REL(g2), (unsigned)(s + 1),
                                        __ATOMIC_RELAXED, __HIP_MEMORY_SCOPE_AGENT);
        }
      }
      while (__hip_atomic_load(relc, __ATOMIC_RELAXED, __HIP_MEMORY_SCOPE_AGENT) < (unsigned)(s + 1))
        __builtin_amdgcn_s_sleep(1);
    }
    __syncthreads();
  }
}

extern "C" void kernel_launch(void* const* d_in, const int* in_sizes, int n_in,
                              void* d_out, int out_size, void* d_ws, size_t ws_size,
                              hipStream_t stream) {
  const float* x   = (const float*)d_in[0];
  const float* Wx0 = (const float*)d_in[1];
  const float* Wh0 = (const float*)d_in[2];
  const float* b0  = (const float*)d_in[3];
  const float* Wx1 = (const float*)d_in[4];
  const float* Wh1 = (const float*)d_in[5];
  const float* b1  = (const float*)d_in[6];
  float* outp = (float*)d_out;

  char* ws = (char*)d_ws;
  unsigned short* xbp   = (unsigned short*)(ws + WS_XB);
  unsigned short* w0tp  = (unsigned short*)(ws + WS_W0T);
  unsigned short* w1tp  = (unsigned short*)(ws + WS_W1T);
  unsigned short* ring0 = (unsigned short*)(ws + WS_RING0);
  unsigned short* ring1 = (unsigned short*)(ws + WS_RING1);
  unsigned*       barp  = (unsigned*)(ws + WS_BAR);

  // prep
  sentinel_kernel<<<dim3(1), dim3(1), 0, stream>>>(outp);
  convert_x_kernel<<<dim3(16384), dim3(256), 0, stream>>>(x, xbp);
  transpose_weights_kernel<<<dim3(48, 128), dim3(32, 8), 0, stream>>>(Wx0, Wh0, w0tp, 512, 1536);
  transpose_weights_kernel<<<dim3(64, 128), dim3(32, 8), 0, stream>>>(Wx1, Wh1, w1tp, 1024, 2048);
  // zero the t=-1 slots (slot 31 of each ring) + barrier words
  hipMemsetAsync(ring0 + 31 * SLOT_ELEMS, 0, SLOT_BYTES, stream);
  hipMemsetAsync(ring1 + 31 * SLOT_ELEMS, 0, SLOT_BYTES, stream);
  hipMemsetAsync(barp, 0, 4096, stream);

  // persistent fused kernel; prefer cooperative launch, fall back to a plain
  // launch (256 blocks x 1 block/CU is co-resident on 256 CUs) if it fails.
  void* kargs[] = { (void*)&xbp, (void*)&w0tp, (void*)&w1tp, (void*)&b0, (void*)&b1,
                    (void*)&ring0, (void*)&ring1, (void*)&barp, (void*)&outp };
  hipError_t e = hipLaunchCooperativeKernel((void*)lstm_persistent, dim3(256), dim3(256),
                                            kargs, 32 * 2050 * 2 /* 131,200 B LDS */, stream);
  if (e != hipSuccess) {
    lstm_persistent<<<dim3(256), dim3(256), 32 * 2050 * 2, stream>>>(
        xbp, w0tp, w1tp, b0, b1, ring0, ring1, barp, outp);
  }
}

// Round 12
// 5863.073 us; speedup vs baseline: 1.8576x; 1.6787x over previous
//
#include <hip/hip_runtime.h>

typedef __attribute__((ext_vector_type(8))) short short8;
typedef __attribute__((ext_vector_type(4))) float f32x4;

// Workspace layout (bytes)
#define WS_XB     0ull          // x in bf16: [64][512][512]            33,554,432 B
#define WS_W0T    33554432ull   // layer0 weights^T fused: [4096][1536] 12,582,912 B
#define WS_W1T    46137344ull   // layer1 weights^T fused: [4096][2048] 16,777,216 B
#define WS_RING0  62914560ull   // h0 ring: [32][64][1024] bf16           4,194,304 B
#define WS_RING1  67108864ull   // h1 ring: [32][64][1024] bf16           4,194,304 B
#define WS_BAR    71303168ull   // barrier counters (<=4096 B used)
#define SLOT_ELEMS 65536        // 64 batches x 1024 units per ring slot
#define SLOT_BYTES 131072

// R8's proven barrier layout: arrive[g]=g*16 (separate 64B lines), root=256,
// release[g]=272+g*16 (separate lines). Laws (R9/R10): <=16 same-line RMWs,
// one-word-per-block polls, fan-out on separate lines.
#define BAR_ARR(g)  ((g) * 16)
#define BAR_ROOT    256
#define BAR_REL(g)  (272 + (g) * 16)

__device__ __forceinline__ unsigned short f2bf(float f) {
  unsigned u = __float_as_uint(f);
  u += 0x7FFFu + ((u >> 16) & 1u);   // round-to-nearest-even
  return (unsigned short)(u >> 16);
}

__device__ __forceinline__ float sigm(float x) { return 1.0f / (1.0f + __expf(-x)); }

// ---- sentinel: "persistent kernel never ran" (absmax ~1e6) marker ----
__global__ void sentinel_kernel(float* out) { out[0] = 1.0e6f; }

// ---- prep: fp32 -> bf16 copy of x (4 elems/thread) ----
__global__ void convert_x_kernel(const float* __restrict__ x, unsigned short* __restrict__ xb) {
  int i = blockIdx.x * 256 + threadIdx.x;
  const float4 v = ((const float4*)x)[i];
  unsigned long long pack = (unsigned long long)f2bf(v.x)
                          | ((unsigned long long)f2bf(v.y) << 16)
                          | ((unsigned long long)f2bf(v.z) << 32)
                          | ((unsigned long long)f2bf(v.w) << 48);
  ((unsigned long long*)xb)[i] = pack;
}

// ---- prep: transpose [K][4096] fp32 (Wx stacked over Wh) -> [4096 perm][Ktot] bf16 ----
__global__ void transpose_weights_kernel(const float* __restrict__ wx, const float* __restrict__ wh,
                                         unsigned short* __restrict__ dst, int Kx, int Ktot) {
  __shared__ float tile[32][33];
  const int k0 = blockIdx.x * 32, n0 = blockIdx.y * 32;
  const int tx = threadIdx.x, ty = threadIdx.y;
#pragma unroll
  for (int i = 0; i < 4; ++i) {
    int k = k0 + ty + i * 8;
    tile[ty + i * 8][tx] = (k < Kx) ? wx[(size_t)k * 4096 + n0 + tx]
                                    : wh[(size_t)(k - Kx) * 4096 + n0 + tx];
  }
  __syncthreads();
#pragma unroll
  for (int i = 0; i < 4; ++i) {
    int n = n0 + ty + i * 8;
    int r = (n & 1023) * 4 + (n >> 10);
    dst[(size_t)r * Ktot + k0 + tx] = f2bf(tile[tx][ty + i * 8]);
  }
}

// ---- per-step MFMA micro-kernel: ALL loads issued upfront (R9 body) ----
// KPAD lesson (R11): LDS row stride MUST be a multiple of 8 elems (16B) or
// ds_read_b128 goes misaligned; 2-way bank aliasing at 2056 is free (m136).
template<int N1, int NBLK>
__device__ __forceinline__ void lstm_step_mfma(int a0b, int a1b,
    const unsigned short* __restrict__ r1p, const unsigned short* __restrict__ r2p,
    f32x4& acc0, f32x4& acc1)
{
  extern __shared__ unsigned short lds[];
  short8 buf[NBLK][8];

#pragma unroll
  for (int bp = 0; bp < NBLK; ++bp) {
    const unsigned short* p = (bp < N1) ? (r1p + bp * 256) : (r2p + (bp - N1) * 256);
#pragma unroll
    for (int j = 0; j < 8; ++j) buf[bp][j] = *(const short8*)(p + j * 32);
  }
  __builtin_amdgcn_sched_barrier(0);           // every load issued before any compute

#pragma unroll
  for (int bp = 0; bp < NBLK; ++bp) {
#pragma unroll
    for (int j = 0; j < 8; ++j)
      asm volatile("" :: "v"(buf[bp][j]));     // wait-wall: block bp materialized here
    __builtin_amdgcn_sched_barrier(0);
#pragma unroll
    for (int j = 0; j < 8; ++j) {
      const int ko = bp * 256 + j * 32;
      short8 a0 = *(const short8*)&lds[a0b + ko];
      short8 a1 = *(const short8*)&lds[a1b + ko];
      acc0 = __builtin_amdgcn_mfma_f32_16x16x32_bf16(a0, buf[bp][j], acc0, 0, 0, 0);
      acc1 = __builtin_amdgcn_mfma_f32_16x16x32_bf16(a1, buf[bp][j], acc1, 0, 0, 0);
    }
  }
}

// ---- persistent fused 2-layer LSTM (R8 structure; only the body differs) ----
__global__ void __launch_bounds__(256, 1) lstm_persistent(
    const unsigned short* __restrict__ xb,
    const unsigned short* __restrict__ w0t,
    const unsigned short* __restrict__ w1t,
    const float* __restrict__ b0v, const float* __restrict__ b1v,
    unsigned short* __restrict__ ring0, unsigned short* __restrict__ ring1,
    unsigned* __restrict__ bar,
    float* __restrict__ out)
{
  extern __shared__ unsigned short lds[];

  const int wg    = blockIdx.x;
  const int group = wg >> 7;       // 0: layer0, 1: layer1
  const int wgl   = wg & 127;
  const int hu0   = wgl * 8;
  const int tid   = threadIdx.x;
  const int lane  = tid & 63;
  const int wid   = tid >> 6;
  const int c16   = lane & 15;
  const int row4  = lane >> 4;
  const int bb    = wid * 16 + c16; // this lane's batch

  const int K    = group ? 2048 : 1536;
  const int KPAD = group ? 2056 : 1544;   // 16B-aligned rows; 2-way banks = free (R11 lesson)

  { // stage weight slice global -> LDS, permuted: LDS row r <- slice row
    // src(r) = 8*((r&15)>>2) + 4*(r>>4) + (r&3)  (tile0 even-of-pair, tile1 odd)
    const unsigned short* wsrc = (group ? w1t : w0t) + (size_t)(wgl * 32) * K;
    const int kv = K >> 3;
    for (int c = tid; c < 32 * kv; c += 256) {
      int r = c / kv, q = c - r * kv;
      int srcr = 8 * ((r & 15) >> 2) + 4 * (r >> 4) + (r & 3);
      *(short8*)&lds[r * KPAD + q * 8] = *(const short8*)&wsrc[(size_t)srcr * K + q * 8];
    }
  }
  __syncthreads();

  const float* bsrc = group ? b1v : b0v;
  float bias0[4], bias1[4];
#pragma unroll
  for (int j = 0; j < 4; ++j) {
    bias0[j] = bsrc[j * 1024 + hu0 + 2 * row4];       // even unit of pair
    bias1[j] = bsrc[j * 1024 + hu0 + 2 * row4 + 1];   // odd unit of pair
  }

  const int a0b = c16 * KPAD + 8 * row4;
  const int a1b = a0b + 16 * KPAD;

  const int lofs = (bb << 10) + 8 * row4;              // read offset within a slot
  const unsigned short* x_cur = xb + ((size_t)bb << 18) + 8 * row4;  // +512/step
  unsigned* rwb = (unsigned*)(group ? ring1 : ring0) + (((bb << 10) + hu0) >> 1) + row4;
  float* out_base = out + ((size_t)bb << 19) + hu0 + 2 * row4;

  // R8 barrier bookkeeping: 16 groups of 16 blocks.
  const int mygrp = wg >> 4;
  unsigned* grpc  = bar + BAR_ARR(mygrp);
  unsigned* rootc = bar + BAR_ROOT;
  unsigned* relc  = bar + BAR_REL(mygrp);

  float cst0 = 0.0f, cst1 = 0.0f;

  for (int s = 0; s <= 512; ++s) {
    const bool active = group ? (s >= 1) : (s < 512);
    if (active) {
      const int t = group ? (s - 1) : s;

      f32x4 acc0 = { bias0[0], bias0[1], bias0[2], bias0[3] };
      f32x4 acc1 = { bias1[0], bias1[1], bias1[2], bias1[3] };

      const unsigned short* h0rd = ring0 + ((s - 1) & 31) * SLOT_ELEMS + lofs;  // h0[s-1]
      if (group == 0) {
        lstm_step_mfma<2, 6>(a0b, a1b, x_cur, h0rd, acc0, acc1);
        x_cur += 512;
      } else {
        const unsigned short* h1rd = ring1 + ((s - 2) & 31) * SLOT_ELEMS + lofs; // h1[s-2]
        lstm_step_mfma<4, 8>(a0b, a1b, h0rd, h1rd, acc0, acc1);
      }

      float hv0, hv1;
      {
        float iv = sigm(acc0[0]), fv = sigm(acc0[1]);
        float gv = tanhf(acc0[2]), ov = sigm(acc0[3]);
        cst0 = fv * cst0 + iv * gv;
        hv0 = ov * tanhf(cst0);
      }
      {
        float iv = sigm(acc1[0]), fv = sigm(acc1[1]);
        float gv = tanhf(acc1[2]), ov = sigm(acc1[3]);
        cst1 = fv * cst1 + iv * gv;
        hv1 = ov * tanhf(cst1);
      }
      // h write: RMW exchange -> coherence point; slot t&31.
      unsigned hp = (unsigned)f2bf(hv0) | ((unsigned)f2bf(hv1) << 16);
      (void)__hip_atomic_exchange(rwb + (t & 31) * (SLOT_ELEMS / 2), hp,
                                  __ATOMIC_RELAXED, __HIP_MEMORY_SCOPE_AGENT);
      if (group) {
        float2 o2; o2.x = hv0; o2.y = hv1;
        *(float2*)(out_base + ((size_t)t << 10)) = o2;   // plain; flushed at dispatch end
      }
    }

    // ---- R8 two-level grid barrier (episode s) ----
    __syncthreads();   // drains all waves' vmem: exchanges at coherence point
    if (tid == 0) {
      unsigned old = __hip_atomic_fetch_add(grpc, 1u, __ATOMIC_RELAXED, __HIP_MEMORY_SCOPE_AGENT);
      if (old == (unsigned)(16 * s + 15)) {                 // group complete
        unsigned old2 = __hip_atomic_fetch_add(rootc, 1u, __ATOMIC_RELAXED, __HIP_MEMORY_SCOPE_AGENT);
        if (old2 == (unsigned)(16 * s + 15)) {              // globally last
#pragma unroll
          for (int g2 = 0; g2 < 16; ++g2)
            (void)__hip_atomic_exchange(bar + BAR_REL(g2), (unsigned)(s + 1),
                                        __ATOMIC_RELAXED, __HIP_MEMORY_SCOPE_AGENT);
        }
      }
      while (__hip_atomic_load(relc, __ATOMIC_RELAXED, __HIP_MEMORY_SCOPE_AGENT) < (unsigned)(s + 1))
        __builtin_amdgcn_s_sleep(1);
    }
    __syncthreads();
  }
}

extern "C" void kernel_launch(void* const* d_in, const int* in_sizes, int n_in,
                              void* d_out, int out_size, void* d_ws, size_t ws_size,
                              hipStream_t stream) {
  const float* x   = (const float*)d_in[0];
  const float* Wx0 = (const float*)d_in[1];
  const float* Wh0 = (const float*)d_in[2];
  const float* b0  = (const float*)d_in[3];
  const float* Wx1 = (const float*)d_in[4];
  const float* Wh1 = (const float*)d_in[5];
  const float* b1  = (const float*)d_in[6];
  float* outp = (float*)d_out;

  char* ws = (char*)d_ws;
  unsigned short* xbp   = (unsigned short*)(ws + WS_XB);
  unsigned short* w0tp  = (unsigned short*)(ws + WS_W0T);
  unsigned short* w1tp  = (unsigned short*)(ws + WS_W1T);
  unsigned short* ring0 = (unsigned short*)(ws + WS_RING0);
  unsigned short* ring1 = (unsigned short*)(ws + WS_RING1);
  unsigned*       barp  = (unsigned*)(ws + WS_BAR);

  // prep
  sentinel_kernel<<<dim3(1), dim3(1), 0, stream>>>(outp);
  convert_x_kernel<<<dim3(16384), dim3(256), 0, stream>>>(x, xbp);
  transpose_weights_kernel<<<dim3(48, 128), dim3(32, 8), 0, stream>>>(Wx0, Wh0, w0tp, 512, 1536);
  transpose_weights_kernel<<<dim3(64, 128), dim3(32, 8), 0, stream>>>(Wx1, Wh1, w1tp, 1024, 2048);
  // zero the t=-1 slots (slot 31 of each ring) + barrier words
  hipMemsetAsync(ring0 + 31 * SLOT_ELEMS, 0, SLOT_BYTES, stream);
  hipMemsetAsync(ring1 + 31 * SLOT_ELEMS, 0, SLOT_BYTES, stream);
  hipMemsetAsync(barp, 0, 4096, stream);

  // persistent fused kernel; prefer cooperative launch, fall back to a plain
  // launch (256 blocks x 1 block/CU is co-resident on 256 CUs) if it fails.
  void* kargs[] = { (void*)&xbp, (void*)&w0tp, (void*)&w1tp, (void*)&b0, (void*)&b1,
                    (void*)&ring0, (void*)&ring1, (void*)&barp, (void*)&outp };
  hipError_t e = hipLaunchCooperativeKernel((void*)lstm_persistent, dim3(256), dim3(256),
                                            kargs, 32 * 2056 * 2 /* 131,584 B LDS */, stream);
  if (e != hipSuccess) {
    lstm_persistent<<<dim3(256), dim3(256), 32 * 2056 * 2, stream>>>(
        xbp, w0tp, w1tp, b0, b1, ring0, ring1, barp, outp);
  }
}

// Round 13
// 5633.390 us; speedup vs baseline: 1.9334x; 1.0408x over previous
//
#include <hip/hip_runtime.h>

typedef __attribute__((ext_vector_type(8))) short short8;
typedef __attribute__((ext_vector_type(4))) float f32x4;

// Workspace layout (bytes)
#define WS_XB     0ull          // x in bf16: [64][512][512]            33,554,432 B
#define WS_W0T    33554432ull   // layer0 weights^T fused: [4096][1536] 12,582,912 B
#define WS_W1T    46137344ull   // layer1 weights^T fused: [4096][2048] 16,777,216 B
#define WS_RING0  62914560ull   // h0 ring: [32][64][1024] bf16           4,194,304 B
#define WS_RING1  67108864ull   // h1 ring: [32][64][1024] bf16           4,194,304 B
#define WS_BAR    71303168ull   // barrier counters (<=4096 B used)
#define SLOT_ELEMS 65536        // 64 batches x 1024 units per ring slot
#define SLOT_BYTES 131072

// Barrier layout (R8-proven): arrive[g]=g*16 (separate 64B lines), root=256,
// release[g]=272+g*16. NEW: l0done at word 544 (its own line, clear of
// release[15] which ends at word 527). Laws: <=16 same-line RMWs/episode,
// one-word polls, fan-out on separate lines.
#define BAR_ARR(g)  ((g) * 16)
#define BAR_ROOT    256
#define BAR_REL(g)  (272 + (g) * 16)
#define BAR_L0DONE  544

__device__ __forceinline__ unsigned short f2bf(float f) {
  unsigned u = __float_as_uint(f);
  u += 0x7FFFu + ((u >> 16) & 1u);   // round-to-nearest-even
  return (unsigned short)(u >> 16);
}

__device__ __forceinline__ float sigm(float x) { return 1.0f / (1.0f + __expf(-x)); }

// ---- sentinel: "persistent kernel never ran" (absmax ~1e6) marker ----
__global__ void sentinel_kernel(float* out) { out[0] = 1.0e6f; }

// ---- prep: fp32 -> bf16 copy of x (4 elems/thread) ----
__global__ void convert_x_kernel(const float* __restrict__ x, unsigned short* __restrict__ xb) {
  int i = blockIdx.x * 256 + threadIdx.x;
  const float4 v = ((const float4*)x)[i];
  unsigned long long pack = (unsigned long long)f2bf(v.x)
                          | ((unsigned long long)f2bf(v.y) << 16)
                          | ((unsigned long long)f2bf(v.z) << 32)
                          | ((unsigned long long)f2bf(v.w) << 48);
  ((unsigned long long*)xb)[i] = pack;
}

// ---- prep: transpose [K][4096] fp32 (Wx stacked over Wh) -> [4096 perm][Ktot] bf16 ----
__global__ void transpose_weights_kernel(const float* __restrict__ wx, const float* __restrict__ wh,
                                         unsigned short* __restrict__ dst, int Kx, int Ktot) {
  __shared__ float tile[32][33];
  const int k0 = blockIdx.x * 32, n0 = blockIdx.y * 32;
  const int tx = threadIdx.x, ty = threadIdx.y;
#pragma unroll
  for (int i = 0; i < 4; ++i) {
    int k = k0 + ty + i * 8;
    tile[ty + i * 8][tx] = (k < Kx) ? wx[(size_t)k * 4096 + n0 + tx]
                                    : wh[(size_t)(k - Kx) * 4096 + n0 + tx];
  }
  __syncthreads();
#pragma unroll
  for (int i = 0; i < 4; ++i) {
    int n = n0 + ty + i * 8;
    int r = (n & 1023) * 4 + (n >> 10);
    dst[(size_t)r * Ktot + k0 + tx] = f2bf(tile[tx][ty + i * 8]);
  }
}

// ---- persistent fused 2-layer LSTM ----
// R8 structure (5,195us proven) + prefetch-under-barrier:
//  * l0done counter: bumped by the 8 L0 group-leaders in the arrive path.
//    L0 (6 blkloads) finishes before L1 (8) -> l0done is set by the time most
//    blocks arrive.
//  * While spinning on release, every block ISSUES next-episode loads:
//    L1: all 4 h0-blocks (gated on l0done); L0: x[t+1] (ungated) + first 2
//    h0-blocks (gated on l0done). Their MALL RTT hides under the release
//    fan-out/detect instead of following it.
//  * Post-release: compute prefetched blocks while the remaining loads
//    (L1's h1, L0's h0 tail -- only available at release) fly.
// Coherence (R7+): h writes = atomic exchange (RMW -> coherence point);
// h reads = plain loads, fresh via depth-32 ring capacity eviction.
// KPAD 2056/1544: 16B-aligned LDS rows (R11/R12 lesson: stride must be a
// multiple of 8 elems for ds_read_b128; 2-way bank aliasing is free).
__global__ void __launch_bounds__(256, 1) lstm_persistent(
    const unsigned short* __restrict__ xb,
    const unsigned short* __restrict__ w0t,
    const unsigned short* __restrict__ w1t,
    const float* __restrict__ b0v, const float* __restrict__ b1v,
    unsigned short* __restrict__ ring0, unsigned short* __restrict__ ring1,
    unsigned* __restrict__ bar,
    float* __restrict__ out)
{
  extern __shared__ unsigned short lds[];

  const int wg    = blockIdx.x;
  const int group = wg >> 7;       // 0: layer0, 1: layer1
  const int wgl   = wg & 127;
  const int hu0   = wgl * 8;
  const int tid   = threadIdx.x;
  const int lane  = tid & 63;
  const int wid   = tid >> 6;
  const int c16   = lane & 15;
  const int row4  = lane >> 4;
  const int bb    = wid * 16 + c16; // this lane's batch

  const int K    = group ? 2048 : 1536;
  const int KPAD = group ? 2056 : 1544;   // 16B-aligned rows; 2-way banks free

  { // stage weight slice global -> LDS, permuted: LDS row r <- slice row
    // src(r) = 8*((r&15)>>2) + 4*(r>>4) + (r&3)  (tile0 even-of-pair, tile1 odd)
    const unsigned short* wsrc = (group ? w1t : w0t) + (size_t)(wgl * 32) * K;
    const int kv = K >> 3;
    for (int c = tid; c < 32 * kv; c += 256) {
      int r = c / kv, q = c - r * kv;
      int srcr = 8 * ((r & 15) >> 2) + 4 * (r >> 4) + (r & 3);
      *(short8*)&lds[r * KPAD + q * 8] = *(const short8*)&wsrc[(size_t)srcr * K + q * 8];
    }
  }
  __syncthreads();

  const float* bsrc = group ? b1v : b0v;
  float bias0[4], bias1[4];
#pragma unroll
  for (int j = 0; j < 4; ++j) {
    bias0[j] = bsrc[j * 1024 + hu0 + 2 * row4];       // even unit of pair
    bias1[j] = bsrc[j * 1024 + hu0 + 2 * row4 + 1];   // odd unit of pair
  }

  const int a0b = c16 * KPAD + 8 * row4;
  const int a1b = a0b + 16 * KPAD;

  const int lofs = (bb << 10) + 8 * row4;              // read offset within a slot
  const unsigned short* xbase = xb + ((size_t)bb << 18) + 8 * row4;  // x[t] = xbase + t*512
  unsigned* rwb = (unsigned*)(group ? ring1 : ring0) + (((bb << 10) + hu0) >> 1) + row4;
  float* out_base = out + ((size_t)bb << 19) + hu0 + 2 * row4;

  // R8 barrier bookkeeping: 16 groups of 16 blocks.
  const int mygrp = wg >> 4;
  unsigned* grpc  = bar + BAR_ARR(mygrp);
  unsigned* rootc = bar + BAR_ROOT;
  unsigned* relc  = bar + BAR_REL(mygrp);
  unsigned* l0d   = bar + BAR_L0DONE;

  float cst0 = 0.0f, cst1 = 0.0f;

  short8 pf0[8], pf1[8], pf2[8], pf3[8];   // prefetch regs, live across the barrier

  auto ld8 = [&](short8* d, const unsigned short* p) {
#pragma unroll
    for (int j = 0; j < 8; ++j) d[j] = *(const short8*)(p + j * 32);
  };

  // Prologue prefetch for episode 0 (L0 only; slot 31 is memset-zero h(-1)).
  if (group == 0) {
    ld8(pf0, xbase); ld8(pf1, xbase + 256);
    const unsigned short* h0p = ring0 + 31 * SLOT_ELEMS + lofs;
    ld8(pf2, h0p); ld8(pf3, h0p + 256);
  }

  for (int s = 0; s <= 512; ++s) {
    const bool active = group ? (s >= 1) : (s < 512);
    if (active) {
      const int t = group ? (s - 1) : s;

      f32x4 acc0 = { bias0[0], bias0[1], bias0[2], bias0[3] };
      f32x4 acc1 = { bias1[0], bias1[1], bias1[2], bias1[3] };

      auto mfma8 = [&](const short8* b, int bp) {
#pragma unroll
        for (int j = 0; j < 8; ++j) {
          const int ko = bp * 256 + j * 32;
          short8 a0 = *(const short8*)&lds[a0b + ko];
          short8 a1 = *(const short8*)&lds[a1b + ko];
          acc0 = __builtin_amdgcn_mfma_f32_16x16x32_bf16(a0, b[j], acc0, 0, 0, 0);
          acc1 = __builtin_amdgcn_mfma_f32_16x16x32_bf16(a1, b[j], acc1, 0, 0, 0);
        }
      };

      const unsigned short* h0rd = ring0 + ((s - 1) & 31) * SLOT_ELEMS + lofs;  // h0[s-1]
      if (group == 0) {
        // pf0,pf1 = x[t]; pf2,pf3 = h0 blocks 0-1; fresh: h0 blocks 2-3.
        short8 f0[8], f1[8];
        ld8(f0, h0rd + 512); ld8(f1, h0rd + 768);
        mfma8(pf0, 0); mfma8(pf1, 1); mfma8(pf2, 2); mfma8(pf3, 3);
        mfma8(f0, 4);  mfma8(f1, 5);
      } else {
        // pf0..pf3 = h0 blocks 0-3; fresh: h1 blocks (only ready at release).
        const unsigned short* h1rd = ring1 + ((s - 2) & 31) * SLOT_ELEMS + lofs; // h1[t-1]
        short8 f0[8], f1[8], f2[8], f3[8];
        ld8(f0, h1rd); ld8(f1, h1rd + 256); ld8(f2, h1rd + 512); ld8(f3, h1rd + 768);
        mfma8(pf0, 0); mfma8(pf1, 1); mfma8(pf2, 2); mfma8(pf3, 3);
        mfma8(f0, 4);  mfma8(f1, 5);  mfma8(f2, 6);  mfma8(f3, 7);
      }

      float hv0, hv1;
      {
        float iv = sigm(acc0[0]), fv = sigm(acc0[1]);
        float gv = tanhf(acc0[2]), ov = sigm(acc0[3]);
        cst0 = fv * cst0 + iv * gv;
        hv0 = ov * tanhf(cst0);
      }
      {
        float iv = sigm(acc1[0]), fv = sigm(acc1[1]);
        float gv = tanhf(acc1[2]), ov = sigm(acc1[3]);
        cst1 = fv * cst1 + iv * gv;
        hv1 = ov * tanhf(cst1);
      }
      // h write: RMW exchange -> coherence point; slot t&31.
      unsigned hp = (unsigned)f2bf(hv0) | ((unsigned)f2bf(hv1) << 16);
      (void)__hip_atomic_exchange(rwb + (t & 31) * (SLOT_ELEMS / 2), hp,
                                  __ATOMIC_RELAXED, __HIP_MEMORY_SCOPE_AGENT);
      if (group) {
        float2 o2; o2.x = hv0; o2.y = hv1;
        *(float2*)(out_base + ((size_t)t << 10)) = o2;   // plain; flushed at dispatch end
      }
    }

    // ---- R8 two-level barrier + prefetch-under-barrier ----
    __syncthreads();   // st1: drains vmem -> exchanges at coherence point
    if (tid == 0) {
      unsigned old = __hip_atomic_fetch_add(grpc, 1u, __ATOMIC_RELAXED, __HIP_MEMORY_SCOPE_AGENT);
      if (old == (unsigned)(16 * s + 15)) {                 // group leader
        if (group == 0)                                     // signal h0[s] complete-ish
          __hip_atomic_fetch_add(l0d, 1u, __ATOMIC_RELAXED, __HIP_MEMORY_SCOPE_AGENT);
        unsigned old2 = __hip_atomic_fetch_add(rootc, 1u, __ATOMIC_RELAXED, __HIP_MEMORY_SCOPE_AGENT);
        if (old2 == (unsigned)(16 * s + 15)) {              // globally last
#pragma unroll
          for (int g2 = 0; g2 < 16; ++g2)
            (void)__hip_atomic_exchange(bar + BAR_REL(g2), (unsigned)(s + 1),
                                        __ATOMIC_RELAXED, __HIP_MEMORY_SCOPE_AGENT);
        }
      }
      if (s < 512) {  // gate for h0[s] prefetch: all 8 L0 groups arrived
        while (__hip_atomic_load(l0d, __ATOMIC_RELAXED, __HIP_MEMORY_SCOPE_AGENT) < 8u * (unsigned)(s + 1))
          __builtin_amdgcn_s_sleep(1);
      }
    }
    __syncthreads();   // st2: l0done observed -> h0[s] is at the coherence point

    if (s < 512) {     // issue next-episode loads; RTT hides under release wait
      const unsigned short* h0n = ring0 + (s & 31) * SLOT_ELEMS + lofs;   // h0[s]
      if (group == 0) {
        if (s + 1 < 512) {
          const unsigned short* xn = xbase + (size_t)(s + 1) * 512;
          ld8(pf0, xn); ld8(pf1, xn + 256);
          ld8(pf2, h0n); ld8(pf3, h0n + 256);
        }
      } else {
        ld8(pf0, h0n); ld8(pf1, h0n + 256); ld8(pf2, h0n + 512); ld8(pf3, h0n + 768);
      }
    }
    __builtin_amdgcn_sched_barrier(0);   // prefetch issue may not sink past the spin

    if (tid == 0) {
      while (__hip_atomic_load(relc, __ATOMIC_RELAXED, __HIP_MEMORY_SCOPE_AGENT) < (unsigned)(s + 1))
        __builtin_amdgcn_s_sleep(1);
    }
    __syncthreads();   // st3
  }
}

extern "C" void kernel_launch(void* const* d_in, const int* in_sizes, int n_in,
                              void* d_out, int out_size, void* d_ws, size_t ws_size,
                              hipStream_t stream) {
  const float* x   = (const float*)d_in[0];
  const float* Wx0 = (const float*)d_in[1];
  const float* Wh0 = (const float*)d_in[2];
  const float* b0  = (const float*)d_in[3];
  const float* Wx1 = (const float*)d_in[4];
  const float* Wh1 = (const float*)d_in[5];
  const float* b1  = (const float*)d_in[6];
  float* outp = (float*)d_out;

  char* ws = (char*)d_ws;
  unsigned short* xbp   = (unsigned short*)(ws + WS_XB);
  unsigned short* w0tp  = (unsigned short*)(ws + WS_W0T);
  unsigned short* w1tp  = (unsigned short*)(ws + WS_W1T);
  unsigned short* ring0 = (unsigned short*)(ws + WS_RING0);
  unsigned short* ring1 = (unsigned short*)(ws + WS_RING1);
  unsigned*       barp  = (unsigned*)(ws + WS_BAR);

  // prep
  sentinel_kernel<<<dim3(1), dim3(1), 0, stream>>>(outp);
  convert_x_kernel<<<dim3(16384), dim3(256), 0, stream>>>(x, xbp);
  transpose_weights_kernel<<<dim3(48, 128), dim3(32, 8), 0, stream>>>(Wx0, Wh0, w0tp, 512, 1536);
  transpose_weights_kernel<<<dim3(64, 128), dim3(32, 8), 0, stream>>>(Wx1, Wh1, w1tp, 1024, 2048);
  // zero the t=-1 slots (slot 31 of each ring) + barrier words
  hipMemsetAsync(ring0 + 31 * SLOT_ELEMS, 0, SLOT_BYTES, stream);
  hipMemsetAsync(ring1 + 31 * SLOT_ELEMS, 0, SLOT_BYTES, stream);
  hipMemsetAsync(barp, 0, 4096, stream);

  // persistent fused kernel; prefer cooperative launch, fall back to a plain
  // launch (256 blocks x 1 block/CU is co-resident on 256 CUs) if it fails.
  void* kargs[] = { (void*)&xbp, (void*)&w0tp, (void*)&w1tp, (void*)&b0, (void*)&b1,
                    (void*)&ring0, (void*)&ring1, (void*)&barp, (void*)&outp };
  hipError_t e = hipLaunchCooperativeKernel((void*)lstm_persistent, dim3(256), dim3(256),
                                            kargs, 32 * 2056 * 2 /* 131,584 B LDS */, stream);
  if (e != hipSuccess) {
    lstm_persistent<<<dim3(256), dim3(256), 32 * 2056 * 2, stream>>>(
        xbp, w0tp, w1tp, b0, b1, ring0, ring1, barp, outp);
  }
}